// Round 3
// baseline (476.407 us; speedup 1.0000x reference)
//
#include <hip/hip_runtime.h>

#define NN 10000
#define NE 640000

typedef __attribute__((ext_vector_type(8))) short bf16x8;
typedef __attribute__((ext_vector_type(4))) short s16x4;
typedef __attribute__((ext_vector_type(4))) float f32x4;

#define MFMA __builtin_amdgcn_mfma_f32_16x16x32_bf16

static __device__ __forceinline__ float silu_f(float x) {
    return x / (1.f + __expf(-x));
}
static __device__ __forceinline__ short f2bf(float x) {   // RNE f32->bf16
    union { float f; unsigned u; } v; v.f = x;
    unsigned r = (v.u + 0x7FFF + ((v.u >> 16) & 1)) >> 16;
    return (short)r;
}
static __device__ __forceinline__ float bf2f(short h) {
    union { float f; unsigned u; } v; v.u = ((unsigned)(unsigned short)h) << 16;
    return v.f;
}

// ---------------- CSR build: histogram / scan / scatter ---------------------
__global__ __launch_bounds__(256) void k_hist(const int* __restrict__ dst,
                                              int* __restrict__ cnt) {
    int e = blockIdx.x * 256 + threadIdx.x;
    if (e < NE) atomicAdd(&cnt[dst[e]], 1);
}

__global__ __launch_bounds__(256) void k_scan(const int* __restrict__ cnt,
                                              int* __restrict__ row_start,
                                              int* __restrict__ cursor) {
    __shared__ int part[256];
    __shared__ int base[257];
    const int t = threadIdx.x;
    int loc[40];
    int s = 0;
    #pragma unroll
    for (int i = 0; i < 40; i++) {
        int idx = t * 40 + i;
        int v = (idx < NN) ? cnt[idx] : 0;
        loc[i] = s; s += v;
    }
    part[t] = s;
    __syncthreads();
    if (t == 0) {
        int a = 0;
        for (int j = 0; j < 256; j++) { base[j] = a; a += part[j]; }
        base[256] = a;
    }
    __syncthreads();
    #pragma unroll
    for (int i = 0; i < 40; i++) {
        int idx = t * 40 + i;
        if (idx < NN) { int v = base[t] + loc[i]; row_start[idx] = v; cursor[idx] = v; }
    }
    if (t == 0) row_start[NN] = base[256];
}

__global__ __launch_bounds__(256) void k_scatter(const int* __restrict__ dst,
                                                 int* __restrict__ cursor,
                                                 int* __restrict__ perm) {
    int e = blockIdx.x * 256 + threadIdx.x;
    if (e < NE) {
        int d = dst[e];
        int p = atomicAdd(&cursor[d], 1);
        perm[p] = e;
    }
}

// ---------------- node precompute -------------------------------------------
// nfb  = bf16(node_feat)
// B[n] = nf @ W_e1[64:128]           (h_dst part of edge-MLP layer 1)
// Qt   = nf @ W_q (internal)
// G[n] = W_k[0:64] @ Qt[n]           (so Kt[s].Qt[d] == nf[s].G[d])
// EQn[n][k] = W_k[65+k,:].Qt[n] ;  WQn[n] = W_k[64,:].Qt[n]
__global__ __launch_bounds__(256) void node_pre_kernel(
    const float* __restrict__ node_feat,
    const float* __restrict__ W_e1,   // [145][64]
    const float* __restrict__ W_k,    // [81][64]
    const float* __restrict__ W_q,    // [64][64]
    short* __restrict__ nfb, float* __restrict__ B,
    float* __restrict__ G, float* __restrict__ EQn, float* __restrict__ WQn)
{
    __shared__ float sW1b[64*64];
    __shared__ float sWq[64*64];
    __shared__ float sWk[64*65];   // [c][j] padded stride 65
    __shared__ float sWke[16*65];  // [k][j] padded
    __shared__ __align__(16) float sx[4][64];
    __shared__ __align__(16) float sq[4][64];

    for (int i = threadIdx.x; i < 64*64; i += 256) {
        sW1b[i] = W_e1[64*64 + i];
        sWq[i]  = W_q[i];
        int c = i >> 6, j = i & 63;
        sWk[c*65 + j] = W_k[i];
    }
    for (int i = threadIdx.x; i < 16*64; i += 256) {
        int k = i >> 6, j = i & 63;
        sWke[k*65 + j] = W_k[(65 + k)*64 + j];
    }
    __syncthreads();

    const int wid = threadIdx.x >> 6;
    const int lane = threadIdx.x & 63;
    for (int n = blockIdx.x * 4 + wid; n < NN; n += gridDim.x * 4) {
        float x = node_feat[n*64 + lane];
        nfb[n*64 + lane] = f2bf(x);
        sx[wid][lane] = x;
        float b = 0.f, q = 0.f;
        #pragma unroll
        for (int i = 0; i < 64; i += 4) {
            float4 x4 = *(const float4*)&sx[wid][i];
            b += x4.x*sW1b[(i+0)*64+lane] + x4.y*sW1b[(i+1)*64+lane]
               + x4.z*sW1b[(i+2)*64+lane] + x4.w*sW1b[(i+3)*64+lane];
            q += x4.x*sWq[(i+0)*64+lane] + x4.y*sWq[(i+1)*64+lane]
               + x4.z*sWq[(i+2)*64+lane] + x4.w*sWq[(i+3)*64+lane];
        }
        B[n*64 + lane] = b;
        sq[wid][lane] = q;

        // G[lane] = sum_j W_k[lane][j] * q[j]
        float g = 0.f;
        #pragma unroll
        for (int j = 0; j < 64; j += 4) {
            float4 q4 = *(const float4*)&sq[wid][j];
            g += q4.x*sWk[lane*65 + j]   + q4.y*sWk[lane*65 + j+1]
               + q4.z*sWk[lane*65 + j+2] + q4.w*sWk[lane*65 + j+3];
        }
        G[n*64 + lane] = g;

        // WQn = sum_j W_k[64][j] * q[j]
        float p = W_k[64*64 + lane] * q;
        #pragma unroll
        for (int off = 32; off; off >>= 1) p += __shfl_xor(p, off);
        if (lane == 0) WQn[n] = p;

        // EQn[k] split across 4 lane-groups
        int kk = lane & 15, pp = lane >> 4;
        float s = 0.f;
        #pragma unroll
        for (int jj = 0; jj < 16; jj++) {
            int j = pp*16 + jj;
            s += sWke[kk*65 + j] * sq[wid][j];
        }
        s += __shfl_xor(s, 16); s += __shfl_xor(s, 32);
        if (lane < 16) EQn[n*16 + kk] = s;
    }
}

// ---------------- edge pass: one wave per dst node --------------------------
// msg-layer1 via K=96 MFMA over [nf_src(64) | ef(16) | dist | 1 | pad]
// weights W1comb = [W_e1[0:64]; W_e1[129:145]; W_e1[128]; b_e1; 0]
// C-init = B[dst] (per-node constant). No atomics, no barriers in loop.
__global__ __launch_bounds__(512, 4) void edge_kernel(
    const short* __restrict__ nfb, const float* __restrict__ coord,
    const float* __restrict__ ef, const int* __restrict__ src,
    const int* __restrict__ perm, const int* __restrict__ row_start,
    const float* __restrict__ W_e1, const float* __restrict__ b_e1,
    const float* __restrict__ W_e2, const float* __restrict__ b_e2,
    const float* __restrict__ B, const float* __restrict__ G,
    const float* __restrict__ EQn, const float* __restrict__ WQn,
    float* __restrict__ hout)
{
    __shared__ short sW1T[64*104];     // [c][k] bf16, k<96 used (pads zero)
    __shared__ short sW2T[64*72];      // [c][k] bf16
    __shared__ short sX[8][16*104];    // per-wave [edge][k]
    __shared__ short sH1[8][16*72];    // per-wave [edge][c]
    __shared__ __align__(16) float sG[8][64];
    __shared__ __align__(16) float sEQ[8][16];
    __shared__ __align__(16) float sw[8][16];

    const int tid = threadIdx.x;
    for (int i = tid; i < 64*104; i += 512) sW1T[i] = 0;
    for (int i = tid; i < 64*72;  i += 512) sW2T[i] = 0;
    __syncthreads();
    for (int i = tid; i < 64*82; i += 512) {
        int k = i >> 6, c = i & 63;
        float v;
        if (k < 64)       v = W_e1[k*64 + c];
        else if (k < 80)  v = W_e1[(129 + k - 64)*64 + c];
        else if (k == 80) v = W_e1[128*64 + c];
        else              v = b_e1[c];
        sW1T[c*104 + k] = f2bf(v);
    }
    for (int i = tid; i < 64*64; i += 512) {
        int k = i >> 6, c = i & 63;
        sW2T[c*72 + k] = f2bf(W_e2[k*64 + c]);
    }

    const int wid = tid >> 6, l = tid & 63;
    const int cl = l & 15, rg = l >> 4;
    const int er = l >> 2, q = l & 3;

    if (l < 16) {   // per-wave X constant cols: bias=1, pads=0
        #pragma unroll
        for (int c = 82; c < 104; c++) sX[wid][l*104 + c] = 0;
        sX[wid][l*104 + 81] = (short)0x3F80;
    }
    __syncthreads();

    const int n = blockIdx.x * 8 + wid;
    const int beg = row_start[n], end = row_start[n+1];

    const float Bb0 = B[n*64 +  0 + cl], Bb1 = B[n*64 + 16 + cl];
    const float Bb2 = B[n*64 + 32 + cl], Bb3 = B[n*64 + 48 + cl];
    const float b20 = b_e2[ 0 + cl], b21 = b_e2[16 + cl];
    const float b22 = b_e2[32 + cl], b23 = b_e2[48 + cl];
    sG[wid][l] = G[n*64 + l];
    if (l < 16) sEQ[wid][l] = EQn[n*16 + l];
    const float wq  = WQn[n];
    const float cdx = coord[n*3+0], cdy = coord[n*3+1], cdz = coord[n*3+2];

    float hs0 = 0.f, hs1 = 0.f, hs2 = 0.f, hs3 = 0.f, den = 0.f;

    for (int c0 = beg; c0 < end; c0 += 16) {
        int idx = c0 + er; if (idx > end - 1) idx = end - 1;
        const int pe = perm[idx];
        const int s  = src[pe];

        // stage nf_src row (already bf16) + edge_feat + dist
        bf16x8 nfA = *(const bf16x8*)&nfb[(size_t)s*64 + q*8];
        bf16x8 nfB = *(const bf16x8*)&nfb[(size_t)s*64 + 32 + q*8];
        *(bf16x8*)&sX[wid][er*104 + q*8]      = nfA;
        *(bf16x8*)&sX[wid][er*104 + 32 + q*8] = nfB;
        float4 efv = *(const float4*)&ef[(size_t)pe*16 + q*4];
        {
            s16x4 p4; p4[0]=f2bf(efv.x); p4[1]=f2bf(efv.y); p4[2]=f2bf(efv.z); p4[3]=f2bf(efv.w);
            *(s16x4*)&sX[wid][er*104 + 64 + q*4] = p4;
        }
        float dist = 0.f;
        if (q == 0) {
            float dx = coord[s*3+0] - cdx, dy = coord[s*3+1] - cdy, dz = coord[s*3+2] - cdz;
            dist = sqrtf(dx*dx + dy*dy + dz*dz);
            sX[wid][er*104 + 80] = f2bf(dist);
        }

        // score = nf_src.G[d] + ef.EQn[d] + dist*WQn[d], split over 4 lanes
        float p;
        {
            const float4 g0 = *(const float4*)&sG[wid][q*8];
            const float4 g1 = *(const float4*)&sG[wid][q*8 + 4];
            const float4 g2 = *(const float4*)&sG[wid][32 + q*8];
            const float4 g3 = *(const float4*)&sG[wid][32 + q*8 + 4];
            p  = bf2f(nfA[0])*g0.x + bf2f(nfA[1])*g0.y + bf2f(nfA[2])*g0.z + bf2f(nfA[3])*g0.w;
            p += bf2f(nfA[4])*g1.x + bf2f(nfA[5])*g1.y + bf2f(nfA[6])*g1.z + bf2f(nfA[7])*g1.w;
            p += bf2f(nfB[0])*g2.x + bf2f(nfB[1])*g2.y + bf2f(nfB[2])*g2.z + bf2f(nfB[3])*g2.w;
            p += bf2f(nfB[4])*g3.x + bf2f(nfB[5])*g3.y + bf2f(nfB[6])*g3.z + bf2f(nfB[7])*g3.w;
            const float4 eq = *(const float4*)&sEQ[wid][q*4];
            p += efv.x*eq.x + efv.y*eq.y + efv.z*eq.z + efv.w*eq.w;
        }
        p += __shfl_xor(p, 1); p += __shfl_xor(p, 2);
        if (q == 0) {
            float wgt = (c0 + er < end) ? __expf((p + dist*wq) * 0.125f) : 0.f;
            sw[wid][er] = wgt;
        }

        // ---- M1: K=96 MFMA, C-init = B[dst] ----
        bf16x8 ax0 = *(const bf16x8*)&sX[wid][cl*104 +  0 + rg*8];
        bf16x8 ax1 = *(const bf16x8*)&sX[wid][cl*104 + 32 + rg*8];
        bf16x8 ax2 = *(const bf16x8*)&sX[wid][cl*104 + 64 + rg*8];
        f32x4 a0 = {Bb0,Bb0,Bb0,Bb0}, a1 = {Bb1,Bb1,Bb1,Bb1};
        f32x4 a2 = {Bb2,Bb2,Bb2,Bb2}, a3 = {Bb3,Bb3,Bb3,Bb3};
        a0 = MFMA(ax0, *(const bf16x8*)&sW1T[( 0+cl)*104 +  0 + rg*8], a0, 0,0,0);
        a0 = MFMA(ax1, *(const bf16x8*)&sW1T[( 0+cl)*104 + 32 + rg*8], a0, 0,0,0);
        a0 = MFMA(ax2, *(const bf16x8*)&sW1T[( 0+cl)*104 + 64 + rg*8], a0, 0,0,0);
        a1 = MFMA(ax0, *(const bf16x8*)&sW1T[(16+cl)*104 +  0 + rg*8], a1, 0,0,0);
        a1 = MFMA(ax1, *(const bf16x8*)&sW1T[(16+cl)*104 + 32 + rg*8], a1, 0,0,0);
        a1 = MFMA(ax2, *(const bf16x8*)&sW1T[(16+cl)*104 + 64 + rg*8], a1, 0,0,0);
        a2 = MFMA(ax0, *(const bf16x8*)&sW1T[(32+cl)*104 +  0 + rg*8], a2, 0,0,0);
        a2 = MFMA(ax1, *(const bf16x8*)&sW1T[(32+cl)*104 + 32 + rg*8], a2, 0,0,0);
        a2 = MFMA(ax2, *(const bf16x8*)&sW1T[(32+cl)*104 + 64 + rg*8], a2, 0,0,0);
        a3 = MFMA(ax0, *(const bf16x8*)&sW1T[(48+cl)*104 +  0 + rg*8], a3, 0,0,0);
        a3 = MFMA(ax1, *(const bf16x8*)&sW1T[(48+cl)*104 + 32 + rg*8], a3, 0,0,0);
        a3 = MFMA(ax2, *(const bf16x8*)&sW1T[(48+cl)*104 + 64 + rg*8], a3, 0,0,0);
        #pragma unroll
        for (int r = 0; r < 4; r++) {
            int row = rg*4 + r;
            sH1[wid][row*72 +  0 + cl] = f2bf(silu_f(a0[r]));
            sH1[wid][row*72 + 16 + cl] = f2bf(silu_f(a1[r]));
            sH1[wid][row*72 + 32 + cl] = f2bf(silu_f(a2[r]));
            sH1[wid][row*72 + 48 + cl] = f2bf(silu_f(a3[r]));
        }

        // ---- M2: msg = silu(b2 + H1 @ W2); weighted accumulate ----
        bf16x8 ah0 = *(const bf16x8*)&sH1[wid][cl*72 + rg*8];
        bf16x8 ah1 = *(const bf16x8*)&sH1[wid][cl*72 + 32 + rg*8];
        f32x4 c0v = {b20,b20,b20,b20}, c1v = {b21,b21,b21,b21};
        f32x4 c2v = {b22,b22,b22,b22}, c3v = {b23,b23,b23,b23};
        c0v = MFMA(ah0, *(const bf16x8*)&sW2T[( 0+cl)*72 +      rg*8], c0v, 0,0,0);
        c0v = MFMA(ah1, *(const bf16x8*)&sW2T[( 0+cl)*72 + 32 + rg*8], c0v, 0,0,0);
        c1v = MFMA(ah0, *(const bf16x8*)&sW2T[(16+cl)*72 +      rg*8], c1v, 0,0,0);
        c1v = MFMA(ah1, *(const bf16x8*)&sW2T[(16+cl)*72 + 32 + rg*8], c1v, 0,0,0);
        c2v = MFMA(ah0, *(const bf16x8*)&sW2T[(32+cl)*72 +      rg*8], c2v, 0,0,0);
        c2v = MFMA(ah1, *(const bf16x8*)&sW2T[(32+cl)*72 + 32 + rg*8], c2v, 0,0,0);
        c3v = MFMA(ah0, *(const bf16x8*)&sW2T[(48+cl)*72 +      rg*8], c3v, 0,0,0);
        c3v = MFMA(ah1, *(const bf16x8*)&sW2T[(48+cl)*72 + 32 + rg*8], c3v, 0,0,0);

        f32x4 wv = *(const f32x4*)&sw[wid][rg*4];
        #pragma unroll
        for (int r = 0; r < 4; r++) {
            hs0 += wv[r] * silu_f(c0v[r]);
            hs1 += wv[r] * silu_f(c1v[r]);
            hs2 += wv[r] * silu_f(c2v[r]);
            hs3 += wv[r] * silu_f(c3v[r]);
        }
        den += wv[0] + wv[1] + wv[2] + wv[3];
    }

    // reduce across the 4 row-groups (lanes l^16, l^32)
    hs0 += __shfl_xor(hs0, 16); hs0 += __shfl_xor(hs0, 32);
    hs1 += __shfl_xor(hs1, 16); hs1 += __shfl_xor(hs1, 32);
    hs2 += __shfl_xor(hs2, 16); hs2 += __shfl_xor(hs2, 32);
    hs3 += __shfl_xor(hs3, 16); hs3 += __shfl_xor(hs3, 32);
    den += __shfl_xor(den, 16); den += __shfl_xor(den, 32);

    float v = (rg == 0) ? hs0 : (rg == 1) ? hs1 : (rg == 2) ? hs2 : hs3;
    hout[n*64 + l] = (den > 0.f) ? v / den : 0.f;
}

// ---------------- node MLP ---------------------------------------------------
__global__ __launch_bounds__(256) void node_out_kernel(
    const float* __restrict__ node_feat,
    const float* __restrict__ W_n1, const float* __restrict__ b_n1,
    const float* __restrict__ W_n2, const float* __restrict__ b_n2,
    const float* __restrict__ hacc, float* __restrict__ out)
{
    __shared__ float sWn1[128*64];
    __shared__ float sWn2[64*64];
    __shared__ __align__(16) float sx[4][64], sg[4][64], st[4][64];

    for (int i = threadIdx.x; i < 128*64; i += 256) sWn1[i] = W_n1[i];
    for (int i = threadIdx.x; i < 64*64; i += 256)  sWn2[i] = W_n2[i];
    __syncthreads();

    const int wid = threadIdx.x >> 6;
    const int lane = threadIdx.x & 63;
    for (int n = blockIdx.x * 4 + wid; n < NN; n += gridDim.x * 4) {
        sx[wid][lane] = node_feat[n*64 + lane];
        sg[wid][lane] = hacc[n*64 + lane];

        float acc = b_n1[lane];
        #pragma unroll
        for (int i = 0; i < 64; i += 4) {
            float4 x4 = *(const float4*)&sx[wid][i];
            float4 g4 = *(const float4*)&sg[wid][i];
            acc += x4.x*sWn1[(i+0)*64+lane] + x4.y*sWn1[(i+1)*64+lane]
                 + x4.z*sWn1[(i+2)*64+lane] + x4.w*sWn1[(i+3)*64+lane];
            acc += g4.x*sWn1[(64+i+0)*64+lane] + g4.y*sWn1[(64+i+1)*64+lane]
                 + g4.z*sWn1[(64+i+2)*64+lane] + g4.w*sWn1[(64+i+3)*64+lane];
        }
        const float tt = silu_f(acc);
        st[wid][lane] = tt;

        float acc2 = b_n2[lane];
        #pragma unroll
        for (int i = 0; i < 64; i += 4) {
            float4 t4 = *(const float4*)&st[wid][i];
            acc2 += t4.x*sWn2[(i+0)*64+lane] + t4.y*sWn2[(i+1)*64+lane]
                  + t4.z*sWn2[(i+2)*64+lane] + t4.w*sWn2[(i+3)*64+lane];
        }
        out[n*64 + lane] = acc2;
    }
}

// ---------------- launch ----------------------------------------------------
extern "C" void kernel_launch(void* const* d_in, const int* in_sizes, int n_in,
                              void* d_out, int out_size, void* d_ws, size_t ws_size,
                              hipStream_t stream) {
    const float* node_feat = (const float*)d_in[0];
    const float* coord     = (const float*)d_in[1];
    const float* edge_feat = (const float*)d_in[2];
    const float* W_e1 = (const float*)d_in[3];
    const float* b_e1 = (const float*)d_in[4];
    const float* W_e2 = (const float*)d_in[5];
    const float* b_e2 = (const float*)d_in[6];
    const float* W_n1 = (const float*)d_in[7];
    const float* b_n1 = (const float*)d_in[8];
    const float* W_n2 = (const float*)d_in[9];
    const float* b_n2 = (const float*)d_in[10];
    const float* W_q  = (const float*)d_in[11];
    const float* W_k  = (const float*)d_in[12];
    const int* src = (const int*)d_in[13];
    const int* dst = (const int*)d_in[14];
    float* out = (float*)d_out;

    float* ws = (float*)d_ws;
    short* nfb      = (short*)ws;             // NN*64 bf16  (320000 f32 slots)
    float* B        = ws + 320000;            // NN*64
    float* G        = ws + 960000;            // NN*64
    float* EQn      = ws + 1600000;           // NN*16
    float* WQn      = ws + 1760000;           // NN
    float* hacc     = ws + 1770000;           // NN*64
    int*   cnt      = (int*)(ws + 2410000);   // NN
    int*   row_start= (int*)(ws + 2420000);   // NN+1
    int*   cursor   = (int*)(ws + 2430001);   // NN
    int*   perm     = (int*)(ws + 2440001);   // NE

    hipMemsetAsync(cnt, 0, NN * sizeof(int), stream);

    k_hist<<<2500, 256, 0, stream>>>(dst, cnt);
    k_scan<<<1, 256, 0, stream>>>(cnt, row_start, cursor);
    k_scatter<<<2500, 256, 0, stream>>>(dst, cursor, perm);
    node_pre_kernel<<<2500, 256, 0, stream>>>(node_feat, W_e1, W_k, W_q,
                                              nfb, B, G, EQn, WQn);
    edge_kernel<<<1250, 512, 0, stream>>>(nfb, coord, edge_feat, src, perm, row_start,
                                          W_e1, b_e1, W_e2, b_e2,
                                          B, G, EQn, WQn, hacc);
    node_out_kernel<<<2500, 256, 0, stream>>>(node_feat, W_n1, b_n1, W_n2, b_n2,
                                              hacc, out);
}

// Round 6
// 425.944 us; speedup vs baseline: 1.1185x; 1.1185x over previous
//
#include <hip/hip_runtime.h>

#define NN 10000
#define NE 640000

typedef __attribute__((ext_vector_type(8))) short bf16x8;
typedef __attribute__((ext_vector_type(4))) short s16x4;
typedef __attribute__((ext_vector_type(4))) float f32x4;

#define MFMA __builtin_amdgcn_mfma_f32_16x16x32_bf16

static __device__ __forceinline__ float silu_f(float x) {
    return x / (1.f + __expf(-x));
}
static __device__ __forceinline__ short f2bf(float x) {   // RNE f32->bf16
    union { float f; unsigned u; } v; v.f = x;
    unsigned r = (v.u + 0x7FFF + ((v.u >> 16) & 1)) >> 16;
    return (short)r;
}

// ---------------- CSR build ---------------------------------------------------
__global__ __launch_bounds__(256) void k_hist(const int* __restrict__ dst,
                                              int* __restrict__ cnt) {
    int e = blockIdx.x * 256 + threadIdx.x;
    if (e < NE) atomicAdd(&cnt[dst[e]], 1);
}

__global__ __launch_bounds__(256) void k_scan(const int* __restrict__ cnt,
                                              int* __restrict__ row_start,
                                              int* __restrict__ cursor) {
    __shared__ int part[256];
    __shared__ int base[257];
    const int t = threadIdx.x;
    int loc[40];
    int s = 0;
    #pragma unroll
    for (int i = 0; i < 40; i++) {
        int idx = t * 40 + i;
        int v = (idx < NN) ? cnt[idx] : 0;
        loc[i] = s; s += v;
    }
    part[t] = s;
    __syncthreads();
    if (t == 0) {
        int a = 0;
        for (int j = 0; j < 256; j++) { base[j] = a; a += part[j]; }
        base[256] = a;
    }
    __syncthreads();
    #pragma unroll
    for (int i = 0; i < 40; i++) {
        int idx = t * 40 + i;
        if (idx < NN) { int v = base[t] + loc[i]; row_start[idx] = v; cursor[idx] = v; }
    }
    if (t == 0) row_start[NN] = base[256];
}

// scatter + full per-edge precompute: attention weight w = exp(score/8),
// bf16 edge features, bf16 dist, src id -- all in dst-sorted order.
__global__ __launch_bounds__(256) void k_scatter(
    const int* __restrict__ dst, const int* __restrict__ src,
    const float* __restrict__ node_feat, const float* __restrict__ ef,
    const float* __restrict__ coord,
    const float* __restrict__ G, const float* __restrict__ EQn,
    const float* __restrict__ WQn,
    int* __restrict__ cursor, int* __restrict__ src_s,
    unsigned short* __restrict__ dist_s, float* __restrict__ w_s,
    unsigned short* __restrict__ efs)
{
    int e = blockIdx.x * 256 + threadIdx.x;
    if (e >= NE) return;
    const int d = dst[e];
    const int s = src[e];
    const int p = atomicAdd(&cursor[d], 1);

    const float dx = coord[s*3+0] - coord[d*3+0];
    const float dy = coord[s*3+1] - coord[d*3+1];
    const float dz = coord[s*3+2] - coord[d*3+2];
    const float dist = sqrtf(dx*dx + dy*dy + dz*dz);

    float sc = dist * WQn[d];
    const float4* xp = (const float4*)(node_feat + (size_t)s*64);
    const float4* gp = (const float4*)(G + (size_t)d*64);
    #pragma unroll
    for (int j = 0; j < 16; j++) {
        float4 a = xp[j], b = gp[j];
        sc += a.x*b.x + a.y*b.y + a.z*b.z + a.w*b.w;
    }
    const float4* ep = (const float4*)(ef + (size_t)e*16);
    const float4* qp = (const float4*)(EQn + (size_t)d*16);
    #pragma unroll
    for (int j = 0; j < 4; j++) {
        float4 a = ep[j], b = qp[j];
        sc += a.x*b.x + a.y*b.y + a.z*b.z + a.w*b.w;
        s16x4 p4;
        p4[0] = f2bf(a.x); p4[1] = f2bf(a.y); p4[2] = f2bf(a.z); p4[3] = f2bf(a.w);
        *(s16x4*)&efs[(size_t)p*16 + j*4] = p4;
    }
    w_s[p] = __expf(sc * 0.125f);
    src_s[p] = s;
    dist_s[p] = (unsigned short)f2bf(dist);
}

// ---------------- node precompute --------------------------------------------
__global__ __launch_bounds__(256) void node_pre_kernel(
    const float* __restrict__ node_feat,
    const float* __restrict__ W_e1,   // [145][64]
    const float* __restrict__ W_k,    // [81][64]
    const float* __restrict__ W_q,    // [64][64]
    short* __restrict__ nfb, float* __restrict__ B,
    float* __restrict__ G, float* __restrict__ EQn, float* __restrict__ WQn)
{
    __shared__ float sW1b[64*64];
    __shared__ float sWq[64*64];
    __shared__ float sWk[64*65];
    __shared__ float sWke[16*65];
    __shared__ __align__(16) float sx[4][64];
    __shared__ __align__(16) float sq[4][64];

    for (int i = threadIdx.x; i < 64*64; i += 256) {
        sW1b[i] = W_e1[64*64 + i];
        sWq[i]  = W_q[i];
        int c = i >> 6, j = i & 63;
        sWk[c*65 + j] = W_k[i];
    }
    for (int i = threadIdx.x; i < 16*64; i += 256) {
        int k = i >> 6, j = i & 63;
        sWke[k*65 + j] = W_k[(65 + k)*64 + j];
    }
    __syncthreads();

    const int wid = threadIdx.x >> 6;
    const int lane = threadIdx.x & 63;
    for (int n = blockIdx.x * 4 + wid; n < NN; n += gridDim.x * 4) {
        float x = node_feat[n*64 + lane];
        nfb[n*64 + lane] = f2bf(x);
        sx[wid][lane] = x;
        float b = 0.f, q = 0.f;
        #pragma unroll
        for (int i = 0; i < 64; i += 4) {
            float4 x4 = *(const float4*)&sx[wid][i];
            b += x4.x*sW1b[(i+0)*64+lane] + x4.y*sW1b[(i+1)*64+lane]
               + x4.z*sW1b[(i+2)*64+lane] + x4.w*sW1b[(i+3)*64+lane];
            q += x4.x*sWq[(i+0)*64+lane] + x4.y*sWq[(i+1)*64+lane]
               + x4.z*sWq[(i+2)*64+lane] + x4.w*sWq[(i+3)*64+lane];
        }
        B[n*64 + lane] = b;
        sq[wid][lane] = q;

        float g = 0.f;
        #pragma unroll
        for (int j = 0; j < 64; j += 4) {
            float4 q4 = *(const float4*)&sq[wid][j];
            g += q4.x*sWk[lane*65 + j]   + q4.y*sWk[lane*65 + j+1]
               + q4.z*sWk[lane*65 + j+2] + q4.w*sWk[lane*65 + j+3];
        }
        G[n*64 + lane] = g;

        float p = W_k[64*64 + lane] * q;
        #pragma unroll
        for (int off = 32; off; off >>= 1) p += __shfl_xor(p, off);
        if (lane == 0) WQn[n] = p;

        int kk = lane & 15, pp = lane >> 4;
        float s = 0.f;
        #pragma unroll
        for (int jj = 0; jj < 16; jj++) {
            int j = pp*16 + jj;
            s += sWke[kk*65 + j] * sq[wid][j];
        }
        s += __shfl_xor(s, 16); s += __shfl_xor(s, 32);
        if (lane < 16) EQn[n*16 + kk] = s;
    }
}

// ---------------- edge pass: one wave per dst node, prefetch pipeline --------
__global__ __launch_bounds__(512, 2) void edge_kernel(
    const short* __restrict__ nfb, const int* __restrict__ src_s,
    const unsigned short* __restrict__ dist_s, const float* __restrict__ w_s,
    const unsigned short* __restrict__ efs, const int* __restrict__ row_start,
    const float* __restrict__ W_e1, const float* __restrict__ b_e1,
    const float* __restrict__ W_e2, const float* __restrict__ b_e2,
    const float* __restrict__ B, float* __restrict__ hout)
{
    __shared__ short sW1T[64*104];     // [c][k], k<96 used, pads zero
    __shared__ short sW2T[64*72];      // [c][k]
    __shared__ short sX[8][16*104];    // per-wave [edge][k]
    __shared__ short sH1[8][16*72];    // per-wave [edge][c]

    const int tid = threadIdx.x;
    const int wid = tid >> 6, l = tid & 63;
    const int cl = l & 15, rg = l >> 4;
    const int er = l >> 2, q = l & 3;

    for (int i = tid; i < 64*104; i += 512) sW1T[i] = 0;
    __syncthreads();
    for (int i = tid; i < 64*82; i += 512) {
        int k = i >> 6, c = i & 63;
        float v;
        if (k < 64)       v = W_e1[k*64 + c];
        else if (k < 80)  v = W_e1[(129 + k - 64)*64 + c];
        else if (k == 80) v = W_e1[128*64 + c];
        else              v = b_e1[c];
        sW1T[c*104 + k] = f2bf(v);
    }
    for (int i = tid; i < 64*64; i += 512) {
        int k = i >> 6, c = i & 63;
        sW2T[c*72 + k] = f2bf(W_e2[k*64 + c]);
    }
    if (l < 16) {
        #pragma unroll
        for (int c = 82; c < 96; c++) sX[wid][l*104 + c] = 0;
        sX[wid][l*104 + 81] = (short)0x3F80;   // bias column = 1.0
    }
    __syncthreads();

    const int n = blockIdx.x * 8 + wid;
    const int beg = row_start[n], end = row_start[n+1];

    const size_t nb = (size_t)n*64;
    const float Bb0 = B[nb+cl],     Bb1 = B[nb+16+cl];
    const float Bb2 = B[nb+32+cl],  Bb3 = B[nb+48+cl];
    const float b20 = b_e2[cl],     b21 = b_e2[16+cl];
    const float b22 = b_e2[32+cl],  b23 = b_e2[48+cl];

    float hs0 = 0.f, hs1 = 0.f, hs2 = 0.f, hs3 = 0.f, den = 0.f;

    // ---- prefetch tile 0 into registers ----
    int idx = beg + er; if (idx > NE-1) idx = NE-1;
    int sN = src_s[idx];
    bf16x8 nfAN = *(const bf16x8*)&nfb[(size_t)sN*64 + q*8];
    bf16x8 nfBN = *(const bf16x8*)&nfb[(size_t)sN*64 + 32 + q*8];
    s16x4  efN  = *(const s16x4*)&efs[(size_t)idx*16 + q*4];
    unsigned short dN = dist_s[idx];
    float wvN[4];
    #pragma unroll
    for (int r = 0; r < 4; r++) {
        int j = beg + rg*4 + r;
        wvN[r] = (j < NE) ? w_s[j] : 0.f;
    }

    for (int c0 = beg; c0 < end; c0 += 16) {
        // rotate prefetched regs to current
        bf16x8 nfA = nfAN, nfB = nfBN; s16x4 ef4 = efN;
        unsigned short dcur = dN;
        float wv[4];
        #pragma unroll
        for (int r = 0; r < 4; r++) wv[r] = wvN[r];

        // issue next-tile loads (overlap with MFMAs below)
        int idx2 = c0 + 16 + er; if (idx2 > NE-1) idx2 = NE-1;
        sN = src_s[idx2];
        nfAN = *(const bf16x8*)&nfb[(size_t)sN*64 + q*8];
        nfBN = *(const bf16x8*)&nfb[(size_t)sN*64 + 32 + q*8];
        efN  = *(const s16x4*)&efs[(size_t)idx2*16 + q*4];
        dN   = dist_s[idx2];
        #pragma unroll
        for (int r = 0; r < 4; r++) {
            int j = c0 + 16 + rg*4 + r;
            wvN[r] = (j < NE) ? w_s[j] : 0.f;
        }

        // stage current tile to LDS (wave-private, no barrier)
        *(bf16x8*)&sX[wid][er*104 + q*8]      = nfA;
        *(bf16x8*)&sX[wid][er*104 + 32 + q*8] = nfB;
        *(s16x4*)&sX[wid][er*104 + 64 + q*4]  = ef4;
        if (q == 0) sX[wid][er*104 + 80] = (short)dcur;

        // ---- M1: K=96 MFMA, C-init = B[dst] ----
        bf16x8 ax0 = *(const bf16x8*)&sX[wid][cl*104 +  0 + rg*8];
        bf16x8 ax1 = *(const bf16x8*)&sX[wid][cl*104 + 32 + rg*8];
        bf16x8 ax2 = *(const bf16x8*)&sX[wid][cl*104 + 64 + rg*8];
        f32x4 a0 = {Bb0,Bb0,Bb0,Bb0}, a1 = {Bb1,Bb1,Bb1,Bb1};
        f32x4 a2 = {Bb2,Bb2,Bb2,Bb2}, a3 = {Bb3,Bb3,Bb3,Bb3};
        a0 = MFMA(ax0, *(const bf16x8*)&sW1T[( 0+cl)*104 +  0 + rg*8], a0, 0,0,0);
        a0 = MFMA(ax1, *(const bf16x8*)&sW1T[( 0+cl)*104 + 32 + rg*8], a0, 0,0,0);
        a0 = MFMA(ax2, *(const bf16x8*)&sW1T[( 0+cl)*104 + 64 + rg*8], a0, 0,0,0);
        a1 = MFMA(ax0, *(const bf16x8*)&sW1T[(16+cl)*104 +  0 + rg*8], a1, 0,0,0);
        a1 = MFMA(ax1, *(const bf16x8*)&sW1T[(16+cl)*104 + 32 + rg*8], a1, 0,0,0);
        a1 = MFMA(ax2, *(const bf16x8*)&sW1T[(16+cl)*104 + 64 + rg*8], a1, 0,0,0);
        a2 = MFMA(ax0, *(const bf16x8*)&sW1T[(32+cl)*104 +  0 + rg*8], a2, 0,0,0);
        a2 = MFMA(ax1, *(const bf16x8*)&sW1T[(32+cl)*104 + 32 + rg*8], a2, 0,0,0);
        a2 = MFMA(ax2, *(const bf16x8*)&sW1T[(32+cl)*104 + 64 + rg*8], a2, 0,0,0);
        a3 = MFMA(ax0, *(const bf16x8*)&sW1T[(48+cl)*104 +  0 + rg*8], a3, 0,0,0);
        a3 = MFMA(ax1, *(const bf16x8*)&sW1T[(48+cl)*104 + 32 + rg*8], a3, 0,0,0);
        a3 = MFMA(ax2, *(const bf16x8*)&sW1T[(48+cl)*104 + 64 + rg*8], a3, 0,0,0);
        #pragma unroll
        for (int r = 0; r < 4; r++) {
            int row = rg*4 + r;
            sH1[wid][row*72 +  0 + cl] = f2bf(silu_f(a0[r]));
            sH1[wid][row*72 + 16 + cl] = f2bf(silu_f(a1[r]));
            sH1[wid][row*72 + 32 + cl] = f2bf(silu_f(a2[r]));
            sH1[wid][row*72 + 48 + cl] = f2bf(silu_f(a3[r]));
        }

        // ---- M2: msg = silu(b2 + H1 @ W2); weighted accumulate ----
        bf16x8 ah0 = *(const bf16x8*)&sH1[wid][cl*72 + rg*8];
        bf16x8 ah1 = *(const bf16x8*)&sH1[wid][cl*72 + 32 + rg*8];
        f32x4 c0v = {b20,b20,b20,b20}, c1v = {b21,b21,b21,b21};
        f32x4 c2v = {b22,b22,b22,b22}, c3v = {b23,b23,b23,b23};
        c0v = MFMA(ah0, *(const bf16x8*)&sW2T[( 0+cl)*72 +      rg*8], c0v, 0,0,0);
        c0v = MFMA(ah1, *(const bf16x8*)&sW2T[( 0+cl)*72 + 32 + rg*8], c0v, 0,0,0);
        c1v = MFMA(ah0, *(const bf16x8*)&sW2T[(16+cl)*72 +      rg*8], c1v, 0,0,0);
        c1v = MFMA(ah1, *(const bf16x8*)&sW2T[(16+cl)*72 + 32 + rg*8], c1v, 0,0,0);
        c2v = MFMA(ah0, *(const bf16x8*)&sW2T[(32+cl)*72 +      rg*8], c2v, 0,0,0);
        c2v = MFMA(ah1, *(const bf16x8*)&sW2T[(32+cl)*72 + 32 + rg*8], c2v, 0,0,0);
        c3v = MFMA(ah0, *(const bf16x8*)&sW2T[(48+cl)*72 +      rg*8], c3v, 0,0,0);
        c3v = MFMA(ah1, *(const bf16x8*)&sW2T[(48+cl)*72 + 32 + rg*8], c3v, 0,0,0);

        #pragma unroll
        for (int r = 0; r < 4; r++) {
            float wr = (c0 + rg*4 + r < end) ? wv[r] : 0.f;
            hs0 += wr * silu_f(c0v[r]);
            hs1 += wr * silu_f(c1v[r]);
            hs2 += wr * silu_f(c2v[r]);
            hs3 += wr * silu_f(c3v[r]);
            den += wr;
        }
    }

    hs0 += __shfl_xor(hs0, 16); hs0 += __shfl_xor(hs0, 32);
    hs1 += __shfl_xor(hs1, 16); hs1 += __shfl_xor(hs1, 32);
    hs2 += __shfl_xor(hs2, 16); hs2 += __shfl_xor(hs2, 32);
    hs3 += __shfl_xor(hs3, 16); hs3 += __shfl_xor(hs3, 32);
    den += __shfl_xor(den, 16); den += __shfl_xor(den, 32);

    float v = (rg == 0) ? hs0 : (rg == 1) ? hs1 : (rg == 2) ? hs2 : hs3;
    hout[nb + l] = (den > 0.f) ? v / den : 0.f;
}

// ---------------- node MLP ---------------------------------------------------
__global__ __launch_bounds__(256) void node_out_kernel(
    const float* __restrict__ node_feat,
    const float* __restrict__ W_n1, const float* __restrict__ b_n1,
    const float* __restrict__ W_n2, const float* __restrict__ b_n2,
    const float* __restrict__ hacc, float* __restrict__ out)
{
    __shared__ float sWn1[128*64];
    __shared__ float sWn2[64*64];
    __shared__ __align__(16) float sx[4][64], sg[4][64], st[4][64];

    for (int i = threadIdx.x; i < 128*64; i += 256) sWn1[i] = W_n1[i];
    for (int i = threadIdx.x; i < 64*64; i += 256)  sWn2[i] = W_n2[i];
    __syncthreads();

    const int wid = threadIdx.x >> 6;
    const int lane = threadIdx.x & 63;
    for (int n = blockIdx.x * 4 + wid; n < NN; n += gridDim.x * 4) {
        sx[wid][lane] = node_feat[n*64 + lane];
        sg[wid][lane] = hacc[n*64 + lane];

        float acc = b_n1[lane];
        #pragma unroll
        for (int i = 0; i < 64; i += 4) {
            float4 x4 = *(const float4*)&sx[wid][i];
            float4 g4 = *(const float4*)&sg[wid][i];
            acc += x4.x*sWn1[(i+0)*64+lane] + x4.y*sWn1[(i+1)*64+lane]
                 + x4.z*sWn1[(i+2)*64+lane] + x4.w*sWn1[(i+3)*64+lane];
            acc += g4.x*sWn1[(64+i+0)*64+lane] + g4.y*sWn1[(64+i+1)*64+lane]
                 + g4.z*sWn1[(64+i+2)*64+lane] + g4.w*sWn1[(64+i+3)*64+lane];
        }
        const float tt = silu_f(acc);
        st[wid][lane] = tt;

        float acc2 = b_n2[lane];
        #pragma unroll
        for (int i = 0; i < 64; i += 4) {
            float4 t4 = *(const float4*)&st[wid][i];
            acc2 += t4.x*sWn2[(i+0)*64+lane] + t4.y*sWn2[(i+1)*64+lane]
                  + t4.z*sWn2[(i+2)*64+lane] + t4.w*sWn2[(i+3)*64+lane];
        }
        out[n*64 + lane] = acc2;
    }
}

// ---------------- launch -----------------------------------------------------
// Workspace layout (f32 units). hacc ALIASES G: G is dead after k_scatter,
// edge_kernel (later in stream) writes hacc there, node_out reads it.
//   nfb       0        .. 320000   (NN*64 bf16)
//   B         320000   .. 960000
//   G/hacc    960000   .. 1600000
//   EQn       1600000  .. 1760000
//   WQn       1760000  .. 1770000
//   cnt       1770000  .. 1780000
//   row_start 1780000  .. 1790001
//   cursor    1790004  .. 1800004
//   src_s     1800004  .. 2440004
//   w_s       2440004  .. 3080004
//   dist_s    3080004  .. 3400004  (NE bf16)
//   efs       3400004  .. 8520004  (NE*16 bf16)   => 34.1 MB total
extern "C" void kernel_launch(void* const* d_in, const int* in_sizes, int n_in,
                              void* d_out, int out_size, void* d_ws, size_t ws_size,
                              hipStream_t stream) {
    const float* node_feat = (const float*)d_in[0];
    const float* coord     = (const float*)d_in[1];
    const float* edge_feat = (const float*)d_in[2];
    const float* W_e1 = (const float*)d_in[3];
    const float* b_e1 = (const float*)d_in[4];
    const float* W_e2 = (const float*)d_in[5];
    const float* b_e2 = (const float*)d_in[6];
    const float* W_n1 = (const float*)d_in[7];
    const float* b_n1 = (const float*)d_in[8];
    const float* W_n2 = (const float*)d_in[9];
    const float* b_n2 = (const float*)d_in[10];
    const float* W_q  = (const float*)d_in[11];
    const float* W_k  = (const float*)d_in[12];
    const int* src = (const int*)d_in[13];
    const int* dst = (const int*)d_in[14];
    float* out = (float*)d_out;

    float* ws = (float*)d_ws;
    short* nfb       = (short*)ws;                       // NN*64 bf16
    float* B         = ws + 320000;
    float* G         = ws + 960000;
    float* hacc      = ws + 960000;                      // alias of G (see above)
    float* EQn       = ws + 1600000;
    float* WQn       = ws + 1760000;
    int*   cnt       = (int*)(ws + 1770000);
    int*   row_start = (int*)(ws + 1780000);
    int*   cursor    = (int*)(ws + 1790004);
    int*   src_s     = (int*)(ws + 1800004);
    float* w_s       = ws + 2440004;
    unsigned short* dist_s = (unsigned short*)(ws + 3080004);
    unsigned short* efs    = (unsigned short*)(ws + 3400004);

    hipMemsetAsync(cnt, 0, NN * sizeof(int), stream);

    node_pre_kernel<<<625, 256, 0, stream>>>(node_feat, W_e1, W_k, W_q,
                                             nfb, B, G, EQn, WQn);
    k_hist<<<2500, 256, 0, stream>>>(dst, cnt);
    k_scan<<<1, 256, 0, stream>>>(cnt, row_start, cursor);
    k_scatter<<<2500, 256, 0, stream>>>(dst, src, node_feat, edge_feat, coord,
                                        G, EQn, WQn, cursor,
                                        src_s, dist_s, w_s, efs);
    edge_kernel<<<1250, 512, 0, stream>>>(nfb, src_s, dist_s, w_s, efs, row_start,
                                          W_e1, b_e1, W_e2, b_e2, B, hacc);
    node_out_kernel<<<625, 256, 0, stream>>>(node_feat, W_n1, b_n1, W_n2, b_n2,
                                             hacc, out);
}

// Round 8
// 367.332 us; speedup vs baseline: 1.2969x; 1.1596x over previous
//
#include <hip/hip_runtime.h>

#define NN 10000
#define NE 640000

typedef __attribute__((ext_vector_type(8))) short bf16x8;
typedef __attribute__((ext_vector_type(4))) short s16x4;
typedef __attribute__((ext_vector_type(4))) float f32x4;

#define MFMA __builtin_amdgcn_mfma_f32_16x16x32_bf16

static __device__ __forceinline__ float silu_f(float x) {
    return x / (1.f + __expf(-x));
}
static __device__ __forceinline__ short f2bf(float x) {   // RNE f32->bf16
    union { float f; unsigned u; } v; v.f = x;
    unsigned r = (v.u + 0x7FFF + ((v.u >> 16) & 1)) >> 16;
    return (short)r;
}
static __device__ __forceinline__ float bf2f(short h) {
    union { float f; unsigned u; } v; v.u = ((unsigned)(unsigned short)h) << 16;
    return v.f;
}

// ---------------- CSR build ---------------------------------------------------
__global__ __launch_bounds__(256) void k_hist(const int* __restrict__ dst,
                                              int* __restrict__ cnt) {
    int e = blockIdx.x * 256 + threadIdx.x;
    if (e < NE) atomicAdd(&cnt[dst[e]], 1);
}

__global__ __launch_bounds__(256) void k_scan(const int* __restrict__ cnt,
                                              int* __restrict__ row_start,
                                              int* __restrict__ cursor) {
    __shared__ int part[256];
    __shared__ int base[257];
    const int t = threadIdx.x;
    int loc[40];
    int s = 0;
    #pragma unroll
    for (int i = 0; i < 40; i++) {
        int idx = t * 40 + i;
        int v = (idx < NN) ? cnt[idx] : 0;
        loc[i] = s; s += v;
    }
    part[t] = s;
    __syncthreads();
    if (t == 0) {
        int a = 0;
        for (int j = 0; j < 256; j++) { base[j] = a; a += part[j]; }
        base[256] = a;
    }
    __syncthreads();
    #pragma unroll
    for (int i = 0; i < 40; i++) {
        int idx = t * 40 + i;
        if (idx < NN) { int v = base[t] + loc[i]; row_start[idx] = v; cursor[idx] = v; }
    }
    if (t == 0) row_start[NN] = base[256];
}

// slim scatter: only the permutation (4B random write per edge)
__global__ __launch_bounds__(256) void k_scatter(const int* __restrict__ dst,
                                                 int* __restrict__ cursor,
                                                 int* __restrict__ perm) {
    int e = blockIdx.x * 256 + threadIdx.x;
    if (e < NE) {
        int d = dst[e];
        int p = atomicAdd(&cursor[d], 1);
        perm[p] = e;
    }
}

// pack in sorted order: random LINE-granular reads, fully coalesced writes.
__global__ __launch_bounds__(256) void k_pack(
    const int* __restrict__ perm, const int* __restrict__ src,
    const int* __restrict__ dst, const float* __restrict__ ef,
    const float* __restrict__ coord,
    int* __restrict__ src_s, unsigned short* __restrict__ dist_s,
    unsigned short* __restrict__ efs)
{
    int p = blockIdx.x * 256 + threadIdx.x;
    if (p >= NE) return;
    const int e = perm[p];
    const int s = src[e];
    const int d = dst[e];

    const float dx = coord[s*3+0] - coord[d*3+0];
    const float dy = coord[s*3+1] - coord[d*3+1];
    const float dz = coord[s*3+2] - coord[d*3+2];
    const float dist = sqrtf(dx*dx + dy*dy + dz*dz);

    src_s[p] = s;
    dist_s[p] = (unsigned short)f2bf(dist);

    const float4* ep = (const float4*)(ef + (size_t)e*16);
    #pragma unroll
    for (int j = 0; j < 4; j++) {
        float4 a = ep[j];
        s16x4 p4;
        p4[0] = f2bf(a.x); p4[1] = f2bf(a.y); p4[2] = f2bf(a.z); p4[3] = f2bf(a.w);
        *(s16x4*)&efs[(size_t)p*16 + j*4] = p4;
    }
}

// ---------------- node precompute --------------------------------------------
__global__ __launch_bounds__(256) void node_pre_kernel(
    const float* __restrict__ node_feat,
    const float* __restrict__ W_e1,   // [145][64]
    const float* __restrict__ W_k,    // [81][64]
    const float* __restrict__ W_q,    // [64][64]
    short* __restrict__ nfb, float* __restrict__ B,
    float* __restrict__ G, float* __restrict__ EQn, float* __restrict__ WQn)
{
    __shared__ float sW1b[64*64];
    __shared__ float sWq[64*64];
    __shared__ float sWk[64*65];
    __shared__ float sWke[16*65];
    __shared__ __align__(16) float sx[4][64];
    __shared__ __align__(16) float sq[4][64];

    for (int i = threadIdx.x; i < 64*64; i += 256) {
        sW1b[i] = W_e1[64*64 + i];
        sWq[i]  = W_q[i];
        int c = i >> 6, j = i & 63;
        sWk[c*65 + j] = W_k[i];
    }
    for (int i = threadIdx.x; i < 16*64; i += 256) {
        int k = i >> 6, j = i & 63;
        sWke[k*65 + j] = W_k[(65 + k)*64 + j];
    }
    __syncthreads();

    const int wid = threadIdx.x >> 6;
    const int lane = threadIdx.x & 63;
    for (int n = blockIdx.x * 4 + wid; n < NN; n += gridDim.x * 4) {
        float x = node_feat[n*64 + lane];
        nfb[n*64 + lane] = f2bf(x);
        sx[wid][lane] = x;
        float b = 0.f, q = 0.f;
        #pragma unroll
        for (int i = 0; i < 64; i += 4) {
            float4 x4 = *(const float4*)&sx[wid][i];
            b += x4.x*sW1b[(i+0)*64+lane] + x4.y*sW1b[(i+1)*64+lane]
               + x4.z*sW1b[(i+2)*64+lane] + x4.w*sW1b[(i+3)*64+lane];
            q += x4.x*sWq[(i+0)*64+lane] + x4.y*sWq[(i+1)*64+lane]
               + x4.z*sWq[(i+2)*64+lane] + x4.w*sWq[(i+3)*64+lane];
        }
        B[n*64 + lane] = b;
        sq[wid][lane] = q;

        float g = 0.f;
        #pragma unroll
        for (int j = 0; j < 64; j += 4) {
            float4 q4 = *(const float4*)&sq[wid][j];
            g += q4.x*sWk[lane*65 + j]   + q4.y*sWk[lane*65 + j+1]
               + q4.z*sWk[lane*65 + j+2] + q4.w*sWk[lane*65 + j+3];
        }
        G[n*64 + lane] = g;

        float p = W_k[64*64 + lane] * q;
        #pragma unroll
        for (int off = 32; off; off >>= 1) p += __shfl_xor(p, off);
        if (lane == 0) WQn[n] = p;

        int kk = lane & 15, pp = lane >> 4;
        float s = 0.f;
        #pragma unroll
        for (int jj = 0; jj < 16; jj++) {
            int j = pp*16 + jj;
            s += sWke[kk*65 + j] * sq[wid][j];
        }
        s += __shfl_xor(s, 16); s += __shfl_xor(s, 32);
        if (lane < 16) EQn[n*16 + kk] = s;
    }
}

// ---------------- edge pass: one wave per dst node, score in-kernel ----------
__global__ __launch_bounds__(512, 2) void edge_kernel(
    const short* __restrict__ nfb, const int* __restrict__ src_s,
    const unsigned short* __restrict__ dist_s,
    const unsigned short* __restrict__ efs, const int* __restrict__ row_start,
    const float* __restrict__ W_e1, const float* __restrict__ b_e1,
    const float* __restrict__ W_e2, const float* __restrict__ b_e2,
    const float* __restrict__ B, const float* __restrict__ G,
    const float* __restrict__ EQn, const float* __restrict__ WQn,
    float* __restrict__ hout)
{
    __shared__ short sW1T[64*104];     // [c][k], k<96 used, pads zero
    __shared__ short sW2T[64*72];      // [c][k]
    __shared__ short sX[8][16*104];    // per-wave [edge][k]
    __shared__ short sH1[8][16*72];    // per-wave [edge][c]
    __shared__ __align__(16) float sG[8][64];
    __shared__ __align__(16) float sEQ[8][16];

    const int tid = threadIdx.x;
    const int wid = tid >> 6, l = tid & 63;
    const int cl = l & 15, rg = l >> 4;
    const int er = l >> 2, q = l & 3;

    for (int i = tid; i < 64*104; i += 512) sW1T[i] = 0;
    __syncthreads();
    for (int i = tid; i < 64*82; i += 512) {
        int k = i >> 6, c = i & 63;
        float v;
        if (k < 64)       v = W_e1[k*64 + c];
        else if (k < 80)  v = W_e1[(129 + k - 64)*64 + c];
        else if (k == 80) v = W_e1[128*64 + c];
        else              v = b_e1[c];
        sW1T[c*104 + k] = f2bf(v);
    }
    for (int i = tid; i < 64*64; i += 512) {
        int k = i >> 6, c = i & 63;
        sW2T[c*72 + k] = f2bf(W_e2[k*64 + c]);
    }
    if (l < 16) {
        #pragma unroll
        for (int c = 82; c < 96; c++) sX[wid][l*104 + c] = 0;
        sX[wid][l*104 + 81] = (short)0x3F80;   // bias column = 1.0
    }
    __syncthreads();

    const int n = blockIdx.x * 8 + wid;
    const int beg = row_start[n], end = row_start[n+1];

    const size_t nb = (size_t)n*64;
    const float Bb0 = B[nb+cl],     Bb1 = B[nb+16+cl];
    const float Bb2 = B[nb+32+cl],  Bb3 = B[nb+48+cl];
    const float b20 = b_e2[cl],     b21 = b_e2[16+cl];
    const float b22 = b_e2[32+cl],  b23 = b_e2[48+cl];
    sG[wid][l] = G[nb + l];
    if (l < 16) sEQ[wid][l] = EQn[(size_t)n*16 + l];
    const float wq = WQn[n];

    float hs0 = 0.f, hs1 = 0.f, hs2 = 0.f, hs3 = 0.f, den = 0.f;

    // ---- prefetch tile 0 into registers ----
    int idx = beg + er; if (idx > NE-1) idx = NE-1;
    int sN = src_s[idx];
    bf16x8 nfAN = *(const bf16x8*)&nfb[(size_t)sN*64 + q*8];
    bf16x8 nfBN = *(const bf16x8*)&nfb[(size_t)sN*64 + 32 + q*8];
    s16x4  efN  = *(const s16x4*)&efs[(size_t)idx*16 + q*4];
    unsigned short dN = dist_s[idx];

    for (int c0 = beg; c0 < end; c0 += 16) {
        // rotate prefetched regs to current
        bf16x8 nfA = nfAN, nfB = nfBN; s16x4 ef4 = efN;
        unsigned short dcur = dN;

        // issue next-tile loads (overlap with compute below)
        int idx2 = c0 + 16 + er; if (idx2 > NE-1) idx2 = NE-1;
        sN = src_s[idx2];
        nfAN = *(const bf16x8*)&nfb[(size_t)sN*64 + q*8];
        nfBN = *(const bf16x8*)&nfb[(size_t)sN*64 + 32 + q*8];
        efN  = *(const s16x4*)&efs[(size_t)idx2*16 + q*4];
        dN   = dist_s[idx2];

        // ---- attention score: nf.G[d] + ef.EQn[d] + dist*WQn[d] ----
        const float dist = bf2f((short)dcur);
        float p_ = 0.f;
        #pragma unroll
        for (int i = 0; i < 8; i++) {
            p_ += bf2f(nfA[i]) * sG[wid][q*8 + i];
            p_ += bf2f(nfB[i]) * sG[wid][32 + q*8 + i];
        }
        #pragma unroll
        for (int i = 0; i < 4; i++)
            p_ += bf2f(ef4[i]) * sEQ[wid][q*4 + i];
        p_ += __shfl_xor(p_, 1); p_ += __shfl_xor(p_, 2);
        const float wgt = __expf((p_ + dist * wq) * 0.125f);

        // stage current tile to LDS (wave-private, no barrier)
        *(bf16x8*)&sX[wid][er*104 + q*8]      = nfA;
        *(bf16x8*)&sX[wid][er*104 + 32 + q*8] = nfB;
        *(s16x4*)&sX[wid][er*104 + 64 + q*4]  = ef4;
        if (q == 0) sX[wid][er*104 + 80] = (short)dcur;

        // ---- M1: K=96 MFMA, C-init = B[dst] ----
        bf16x8 ax0 = *(const bf16x8*)&sX[wid][cl*104 +  0 + rg*8];
        bf16x8 ax1 = *(const bf16x8*)&sX[wid][cl*104 + 32 + rg*8];
        bf16x8 ax2 = *(const bf16x8*)&sX[wid][cl*104 + 64 + rg*8];
        f32x4 a0 = {Bb0,Bb0,Bb0,Bb0}, a1 = {Bb1,Bb1,Bb1,Bb1};
        f32x4 a2 = {Bb2,Bb2,Bb2,Bb2}, a3 = {Bb3,Bb3,Bb3,Bb3};
        a0 = MFMA(ax0, *(const bf16x8*)&sW1T[( 0+cl)*104 +  0 + rg*8], a0, 0,0,0);
        a0 = MFMA(ax1, *(const bf16x8*)&sW1T[( 0+cl)*104 + 32 + rg*8], a0, 0,0,0);
        a0 = MFMA(ax2, *(const bf16x8*)&sW1T[( 0+cl)*104 + 64 + rg*8], a0, 0,0,0);
        a1 = MFMA(ax0, *(const bf16x8*)&sW1T[(16+cl)*104 +  0 + rg*8], a1, 0,0,0);
        a1 = MFMA(ax1, *(const bf16x8*)&sW1T[(16+cl)*104 + 32 + rg*8], a1, 0,0,0);
        a1 = MFMA(ax2, *(const bf16x8*)&sW1T[(16+cl)*104 + 64 + rg*8], a1, 0,0,0);
        a2 = MFMA(ax0, *(const bf16x8*)&sW1T[(32+cl)*104 +  0 + rg*8], a2, 0,0,0);
        a2 = MFMA(ax1, *(const bf16x8*)&sW1T[(32+cl)*104 + 32 + rg*8], a2, 0,0,0);
        a2 = MFMA(ax2, *(const bf16x8*)&sW1T[(32+cl)*104 + 64 + rg*8], a2, 0,0,0);
        a3 = MFMA(ax0, *(const bf16x8*)&sW1T[(48+cl)*104 +  0 + rg*8], a3, 0,0,0);
        a3 = MFMA(ax1, *(const bf16x8*)&sW1T[(48+cl)*104 + 32 + rg*8], a3, 0,0,0);
        a3 = MFMA(ax2, *(const bf16x8*)&sW1T[(48+cl)*104 + 64 + rg*8], a3, 0,0,0);
        #pragma unroll
        for (int r = 0; r < 4; r++) {
            int row = rg*4 + r;
            sH1[wid][row*72 +  0 + cl] = f2bf(silu_f(a0[r]));
            sH1[wid][row*72 + 16 + cl] = f2bf(silu_f(a1[r]));
            sH1[wid][row*72 + 32 + cl] = f2bf(silu_f(a2[r]));
            sH1[wid][row*72 + 48 + cl] = f2bf(silu_f(a3[r]));
        }

        // ---- M2: msg = silu(b2 + H1 @ W2); weighted accumulate ----
        bf16x8 ah0 = *(const bf16x8*)&sH1[wid][cl*72 + rg*8];
        bf16x8 ah1 = *(const bf16x8*)&sH1[wid][cl*72 + 32 + rg*8];
        f32x4 c0v = {b20,b20,b20,b20}, c1v = {b21,b21,b21,b21};
        f32x4 c2v = {b22,b22,b22,b22}, c3v = {b23,b23,b23,b23};
        c0v = MFMA(ah0, *(const bf16x8*)&sW2T[( 0+cl)*72 +      rg*8], c0v, 0,0,0);
        c0v = MFMA(ah1, *(const bf16x8*)&sW2T[( 0+cl)*72 + 32 + rg*8], c0v, 0,0,0);
        c1v = MFMA(ah0, *(const bf16x8*)&sW2T[(16+cl)*72 +      rg*8], c1v, 0,0,0);
        c1v = MFMA(ah1, *(const bf16x8*)&sW2T[(16+cl)*72 + 32 + rg*8], c1v, 0,0,0);
        c2v = MFMA(ah0, *(const bf16x8*)&sW2T[(32+cl)*72 +      rg*8], c2v, 0,0,0);
        c2v = MFMA(ah1, *(const bf16x8*)&sW2T[(32+cl)*72 + 32 + rg*8], c2v, 0,0,0);
        c3v = MFMA(ah0, *(const bf16x8*)&sW2T[(48+cl)*72 +      rg*8], c3v, 0,0,0);
        c3v = MFMA(ah1, *(const bf16x8*)&sW2T[(48+cl)*72 + 32 + rg*8], c3v, 0,0,0);

        #pragma unroll
        for (int r = 0; r < 4; r++) {
            int row = rg*4 + r;
            float wr = (c0 + row < end) ? __shfl(wgt, row << 2) : 0.f;
            hs0 += wr * silu_f(c0v[r]);
            hs1 += wr * silu_f(c1v[r]);
            hs2 += wr * silu_f(c2v[r]);
            hs3 += wr * silu_f(c3v[r]);
            den += wr;
        }
    }

    hs0 += __shfl_xor(hs0, 16); hs0 += __shfl_xor(hs0, 32);
    hs1 += __shfl_xor(hs1, 16); hs1 += __shfl_xor(hs1, 32);
    hs2 += __shfl_xor(hs2, 16); hs2 += __shfl_xor(hs2, 32);
    hs3 += __shfl_xor(hs3, 16); hs3 += __shfl_xor(hs3, 32);
    den += __shfl_xor(den, 16); den += __shfl_xor(den, 32);

    float v = (rg == 0) ? hs0 : (rg == 1) ? hs1 : (rg == 2) ? hs2 : hs3;
    hout[nb + l] = (den > 0.f) ? v / den : 0.f;
}

// ---------------- node MLP ---------------------------------------------------
__global__ __launch_bounds__(256) void node_out_kernel(
    const float* __restrict__ node_feat,
    const float* __restrict__ W_n1, const float* __restrict__ b_n1,
    const float* __restrict__ W_n2, const float* __restrict__ b_n2,
    const float* __restrict__ hacc, float* __restrict__ out)
{
    __shared__ float sWn1[128*64];
    __shared__ float sWn2[64*64];
    __shared__ __align__(16) float sx[4][64], sg[4][64], st[4][64];

    for (int i = threadIdx.x; i < 128*64; i += 256) sWn1[i] = W_n1[i];
    for (int i = threadIdx.x; i < 64*64; i += 256)  sWn2[i] = W_n2[i];
    __syncthreads();

    const int wid = threadIdx.x >> 6;
    const int lane = threadIdx.x & 63;
    for (int n = blockIdx.x * 4 + wid; n < NN; n += gridDim.x * 4) {
        sx[wid][lane] = node_feat[n*64 + lane];
        sg[wid][lane] = hacc[n*64 + lane];

        float acc = b_n1[lane];
        #pragma unroll
        for (int i = 0; i < 64; i += 4) {
            float4 x4 = *(const float4*)&sx[wid][i];
            float4 g4 = *(const float4*)&sg[wid][i];
            acc += x4.x*sWn1[(i+0)*64+lane] + x4.y*sWn1[(i+1)*64+lane]
                 + x4.z*sWn1[(i+2)*64+lane] + x4.w*sWn1[(i+3)*64+lane];
            acc += g4.x*sWn1[(64+i+0)*64+lane] + g4.y*sWn1[(64+i+1)*64+lane]
                 + g4.z*sWn1[(64+i+2)*64+lane] + g4.w*sWn1[(64+i+3)*64+lane];
        }
        const float tt = silu_f(acc);
        st[wid][lane] = tt;

        float acc2 = b_n2[lane];
        #pragma unroll
        for (int i = 0; i < 64; i += 4) {
            float4 t4 = *(const float4*)&st[wid][i];
            acc2 += t4.x*sWn2[(i+0)*64+lane] + t4.y*sWn2[(i+1)*64+lane]
                  + t4.z*sWn2[(i+2)*64+lane] + t4.w*sWn2[(i+3)*64+lane];
        }
        out[n*64 + lane] = acc2;
    }
}

// ---------------- launch -----------------------------------------------------
// Workspace layout (f32 units), all regions disjoint:
//   nfb       0        .. 320000   (NN*64 bf16)
//   B         320000   .. 960000
//   G         960000   .. 1600000
//   EQn       1600000  .. 1760000
//   WQn       1760000  .. 1770000
//   cnt       1770000  .. 1780000
//   row_start 1780000  .. 1790004
//   cursor    1790004  .. 1800004
//   perm      1800004  .. 2440004
//   src_s     2440004  .. 3080004
//   dist_s    3080004  .. 3400004  (NE bf16)
//   efs       3400004  .. 8520004  (NE*16 bf16)
//   hacc      8520004  .. 9160004   => 36.6 MB total
extern "C" void kernel_launch(void* const* d_in, const int* in_sizes, int n_in,
                              void* d_out, int out_size, void* d_ws, size_t ws_size,
                              hipStream_t stream) {
    const float* node_feat = (const float*)d_in[0];
    const float* coord     = (const float*)d_in[1];
    const float* edge_feat = (const float*)d_in[2];
    const float* W_e1 = (const float*)d_in[3];
    const float* b_e1 = (const float*)d_in[4];
    const float* W_e2 = (const float*)d_in[5];
    const float* b_e2 = (const float*)d_in[6];
    const float* W_n1 = (const float*)d_in[7];
    const float* b_n1 = (const float*)d_in[8];
    const float* W_n2 = (const float*)d_in[9];
    const float* b_n2 = (const float*)d_in[10];
    const float* W_q  = (const float*)d_in[11];
    const float* W_k  = (const float*)d_in[12];
    const int* src = (const int*)d_in[13];
    const int* dst = (const int*)d_in[14];
    float* out = (float*)d_out;

    float* ws = (float*)d_ws;
    short* nfb       = (short*)ws;
    float* B         = ws + 320000;
    float* G         = ws + 960000;
    float* EQn       = ws + 1600000;
    float* WQn       = ws + 1760000;
    int*   cnt       = (int*)(ws + 1770000);
    int*   row_start = (int*)(ws + 1780000);
    int*   cursor    = (int*)(ws + 1790004);
    int*   perm      = (int*)(ws + 1800004);
    int*   src_s     = (int*)(ws + 2440004);
    unsigned short* dist_s = (unsigned short*)(ws + 3080004);
    unsigned short* efs    = (unsigned short*)(ws + 3400004);
    float* hacc      = ws + 8520004;

    hipMemsetAsync(cnt, 0, NN * sizeof(int), stream);

    node_pre_kernel<<<625, 256, 0, stream>>>(node_feat, W_e1, W_k, W_q,
                                             nfb, B, G, EQn, WQn);
    k_hist<<<2500, 256, 0, stream>>>(dst, cnt);
    k_scan<<<1, 256, 0, stream>>>(cnt, row_start, cursor);
    k_scatter<<<2500, 256, 0, stream>>>(dst, cursor, perm);
    k_pack<<<2500, 256, 0, stream>>>(perm, src, dst, edge_feat, coord,
                                     src_s, dist_s, efs);
    edge_kernel<<<1250, 512, 0, stream>>>(nfb, src_s, dist_s, efs, row_start,
                                          W_e1, b_e1, W_e2, b_e2,
                                          B, G, EQn, WQn, hacc);
    node_out_kernel<<<625, 256, 0, stream>>>(node_feat, W_n1, b_n1, W_n2, b_n2,
                                             hacc, out);
}

// Round 9
// 348.188 us; speedup vs baseline: 1.3682x; 1.0550x over previous
//
#include <hip/hip_runtime.h>

#define NN 10000
#define NE 640000

typedef __attribute__((ext_vector_type(8))) short bf16x8;
typedef __attribute__((ext_vector_type(4))) short s16x4;
typedef __attribute__((ext_vector_type(4))) float f32x4;

#define MFMA __builtin_amdgcn_mfma_f32_16x16x32_bf16

static __device__ __forceinline__ float silu_f(float x) {
    return x / (1.f + __expf(-x));
}
// fast silu: v_rcp_f32 (1 ulp) instead of IEEE divide — output is bf16-rounded anyway
static __device__ __forceinline__ float silu_fast(float x) {
    float d = 1.f + __expf(-x);
    float r; asm("v_rcp_f32 %0, %1" : "=v"(r) : "v"(d));
    return x * r;
}
static __device__ __forceinline__ short f2bf(float x) {   // RNE f32->bf16
    union { float f; unsigned u; } v; v.f = x;
    unsigned r = (v.u + 0x7FFF + ((v.u >> 16) & 1)) >> 16;
    return (short)r;
}
static __device__ __forceinline__ float bf2f(short h) {
    union { float f; unsigned u; } v; v.u = ((unsigned)(unsigned short)h) << 16;
    return v.f;
}

// ---------------- CSR build ---------------------------------------------------
__global__ __launch_bounds__(256) void k_hist(const int* __restrict__ dst,
                                              int* __restrict__ cnt) {
    int e = blockIdx.x * 256 + threadIdx.x;
    if (e < NE) atomicAdd(&cnt[dst[e]], 1);
}

__global__ __launch_bounds__(256) void k_scan(const int* __restrict__ cnt,
                                              int* __restrict__ row_start,
                                              int* __restrict__ cursor) {
    __shared__ int sv[NN];        // 40 KB, LDS-staged for coalesced global I/O
    __shared__ int part[256];
    __shared__ int base[257];
    const int t = threadIdx.x;
    for (int i = t; i < NN; i += 256) sv[i] = cnt[i];
    __syncthreads();
    int s = 0;
    #pragma unroll
    for (int i = 0; i < 40; i++) {
        int idx = t * 40 + i;
        int v = (idx < NN) ? sv[idx] : 0;
        if (idx < NN) sv[idx] = s;        // local exclusive
        s += v;
    }
    part[t] = s;
    __syncthreads();
    if (t == 0) {
        int a = 0;
        for (int j = 0; j < 256; j++) { base[j] = a; a += part[j]; }
        base[256] = a;
    }
    __syncthreads();
    for (int i = t; i < NN; i += 256) {
        int v = base[i / 40] + sv[i];
        row_start[i] = v; cursor[i] = v;
    }
    if (t == 0) row_start[NN] = base[256];
}

// slim scatter: only the permutation (4B random write per edge)
__global__ __launch_bounds__(256) void k_scatter(const int* __restrict__ dst,
                                                 int* __restrict__ cursor,
                                                 int* __restrict__ perm) {
    int e = blockIdx.x * 256 + threadIdx.x;
    if (e < NE) {
        int d = dst[e];
        int p = atomicAdd(&cursor[d], 1);
        perm[p] = e;
    }
}

// pack in sorted order: random LINE-granular reads, fully coalesced writes.
__global__ __launch_bounds__(256) void k_pack(
    const int* __restrict__ perm, const int* __restrict__ src,
    const int* __restrict__ dst, const float* __restrict__ ef,
    const float* __restrict__ coord,
    int* __restrict__ src_s, unsigned short* __restrict__ dist_s,
    unsigned short* __restrict__ efs)
{
    int p = blockIdx.x * 256 + threadIdx.x;
    if (p >= NE) return;
    const int e = perm[p];
    const int s = src[e];
    const int d = dst[e];

    const float dx = coord[s*3+0] - coord[d*3+0];
    const float dy = coord[s*3+1] - coord[d*3+1];
    const float dz = coord[s*3+2] - coord[d*3+2];
    const float dist = sqrtf(dx*dx + dy*dy + dz*dz);

    src_s[p] = s;
    dist_s[p] = (unsigned short)f2bf(dist);

    const float4* ep = (const float4*)(ef + (size_t)e*16);
    #pragma unroll
    for (int j = 0; j < 4; j++) {
        float4 a = ep[j];
        s16x4 p4;
        p4[0] = f2bf(a.x); p4[1] = f2bf(a.y); p4[2] = f2bf(a.z); p4[3] = f2bf(a.w);
        *(s16x4*)&efs[(size_t)p*16 + j*4] = p4;
    }
}

// ---------------- node precompute --------------------------------------------
__global__ __launch_bounds__(256) void node_pre_kernel(
    const float* __restrict__ node_feat,
    const float* __restrict__ W_e1,   // [145][64]
    const float* __restrict__ W_k,    // [81][64]
    const float* __restrict__ W_q,    // [64][64]
    short* __restrict__ nfb, float* __restrict__ B,
    float* __restrict__ G, float* __restrict__ EQn, float* __restrict__ WQn)
{
    __shared__ float sW1b[64*64];
    __shared__ float sWq[64*64];
    __shared__ float sWk[64*65];
    __shared__ float sWke[16*65];
    __shared__ __align__(16) float sx[4][64];
    __shared__ __align__(16) float sq[4][64];

    for (int i = threadIdx.x; i < 64*64; i += 256) {
        sW1b[i] = W_e1[64*64 + i];
        sWq[i]  = W_q[i];
        int c = i >> 6, j = i & 63;
        sWk[c*65 + j] = W_k[i];
    }
    for (int i = threadIdx.x; i < 16*64; i += 256) {
        int k = i >> 6, j = i & 63;
        sWke[k*65 + j] = W_k[(65 + k)*64 + j];
    }
    __syncthreads();

    const int wid = threadIdx.x >> 6;
    const int lane = threadIdx.x & 63;
    for (int n = blockIdx.x * 4 + wid; n < NN; n += gridDim.x * 4) {
        float x = node_feat[n*64 + lane];
        nfb[n*64 + lane] = f2bf(x);
        sx[wid][lane] = x;
        float b = 0.f, q = 0.f;
        #pragma unroll
        for (int i = 0; i < 64; i += 4) {
            float4 x4 = *(const float4*)&sx[wid][i];
            b += x4.x*sW1b[(i+0)*64+lane] + x4.y*sW1b[(i+1)*64+lane]
               + x4.z*sW1b[(i+2)*64+lane] + x4.w*sW1b[(i+3)*64+lane];
            q += x4.x*sWq[(i+0)*64+lane] + x4.y*sWq[(i+1)*64+lane]
               + x4.z*sWq[(i+2)*64+lane] + x4.w*sWq[(i+3)*64+lane];
        }
        B[n*64 + lane] = b;
        sq[wid][lane] = q;

        float g = 0.f;
        #pragma unroll
        for (int j = 0; j < 64; j += 4) {
            float4 q4 = *(const float4*)&sq[wid][j];
            g += q4.x*sWk[lane*65 + j]   + q4.y*sWk[lane*65 + j+1]
               + q4.z*sWk[lane*65 + j+2] + q4.w*sWk[lane*65 + j+3];
        }
        G[n*64 + lane] = g;

        float p = W_k[64*64 + lane] * q;
        #pragma unroll
        for (int off = 32; off; off >>= 1) p += __shfl_xor(p, off);
        if (lane == 0) WQn[n] = p;

        int kk = lane & 15, pp = lane >> 4;
        float s = 0.f;
        #pragma unroll
        for (int jj = 0; jj < 16; jj++) {
            int j = pp*16 + jj;
            s += sWke[kk*65 + j] * sq[wid][j];
        }
        s += __shfl_xor(s, 16); s += __shfl_xor(s, 32);
        if (lane < 16) EQn[n*16 + kk] = s;
    }
}

// ---------------- edge pass: one wave per dst node ---------------------------
// N-dim of W1/W2 is PERMUTED so lane (cl,rg)'s 4 accs hold logical cols
// cl*4+{0..3}: sH1 store = 2x v_cvt_pk_bf16_f32 + 1x ds_write_b64.
__global__ __launch_bounds__(512, 2) void edge_kernel(
    const short* __restrict__ nfb, const int* __restrict__ src_s,
    const unsigned short* __restrict__ dist_s,
    const unsigned short* __restrict__ efs, const int* __restrict__ row_start,
    const float* __restrict__ W_e1, const float* __restrict__ b_e1,
    const float* __restrict__ W_e2, const float* __restrict__ b_e2,
    const float* __restrict__ B, const float* __restrict__ G,
    const float* __restrict__ EQn, const float* __restrict__ WQn,
    float* __restrict__ hout)
{
    __shared__ short sW1T[64*104];     // [phys slot][k], k<96 used, pads zero
    __shared__ short sW2T[64*72];      // [phys slot][k]
    __shared__ short sX[8][16*104];    // per-wave [edge][k]
    __shared__ short sH1[8][16*72];    // per-wave [edge][logical c]
    __shared__ __align__(16) float sG[8][64];
    __shared__ __align__(16) float sEQ[8][16];

    const int tid = threadIdx.x;
    const int wid = tid >> 6, l = tid & 63;
    const int cl = l & 15, rg = l >> 4;
    const int er = l >> 2, q = l & 3;

    for (int i = tid; i < 64*104; i += 512) sW1T[i] = 0;
    __syncthreads();
    for (int i = tid; i < 64*82; i += 512) {
        int k = i >> 6, c = i & 63;              // c = LOGICAL output col
        float v;
        if (k < 64)       v = W_e1[k*64 + c];
        else if (k < 80)  v = W_e1[(129 + k - 64)*64 + c];
        else if (k == 80) v = W_e1[128*64 + c];
        else              v = b_e1[c];
        int s = (c & 3) * 16 + (c >> 2);          // physical MFMA col slot
        sW1T[s*104 + k] = f2bf(v);
    }
    for (int i = tid; i < 64*64; i += 512) {
        int k = i >> 6, c = i & 63;              // k logical (matches sH1), c logical out col
        int s = (c & 3) * 16 + (c >> 2);
        sW2T[s*72 + k] = f2bf(W_e2[k*64 + c]);
    }
    if (l < 16) {
        #pragma unroll
        for (int c = 82; c < 96; c++) sX[wid][l*104 + c] = 0;
        sX[wid][l*104 + 81] = (short)0x3F80;   // bias column = 1.0
    }
    __syncthreads();

    const int n = blockIdx.x * 8 + wid;
    const int beg = row_start[n], end = row_start[n+1];

    const size_t nb = (size_t)n*64;
    const float4 Bb4 = *(const float4*)&B[nb + cl*4];      // logical cols cl*4..+3
    const float4 b24 = *(const float4*)&b_e2[cl*4];
    sG[wid][l] = G[nb + l];
    if (l < 16) sEQ[wid][l] = EQn[(size_t)n*16 + l];
    const float wq = WQn[n];

    float hs0 = 0.f, hs1 = 0.f, hs2 = 0.f, hs3 = 0.f, den = 0.f;

    // ---- prefetch tile 0 into registers ----
    int idx = beg + er; if (idx > NE-1) idx = NE-1;
    int sN = src_s[idx];
    bf16x8 nfAN = *(const bf16x8*)&nfb[(size_t)sN*64 + q*8];
    bf16x8 nfBN = *(const bf16x8*)&nfb[(size_t)sN*64 + 32 + q*8];
    s16x4  efN  = *(const s16x4*)&efs[(size_t)idx*16 + q*4];
    unsigned short dN = dist_s[idx];

    for (int c0 = beg; c0 < end; c0 += 16) {
        bf16x8 nfA = nfAN, nfB = nfBN; s16x4 ef4 = efN;
        unsigned short dcur = dN;

        int idx2 = c0 + 16 + er; if (idx2 > NE-1) idx2 = NE-1;
        sN = src_s[idx2];
        nfAN = *(const bf16x8*)&nfb[(size_t)sN*64 + q*8];
        nfBN = *(const bf16x8*)&nfb[(size_t)sN*64 + 32 + q*8];
        efN  = *(const s16x4*)&efs[(size_t)idx2*16 + q*4];
        dN   = dist_s[idx2];

        // ---- attention score: nf.G[d] + ef.EQn[d] + dist*WQn[d] ----
        const float dist = bf2f((short)dcur);
        float p_ = 0.f;
        #pragma unroll
        for (int i = 0; i < 8; i++) {
            p_ += bf2f(nfA[i]) * sG[wid][q*8 + i];
            p_ += bf2f(nfB[i]) * sG[wid][32 + q*8 + i];
        }
        #pragma unroll
        for (int i = 0; i < 4; i++)
            p_ += bf2f(ef4[i]) * sEQ[wid][q*4 + i];
        p_ += __shfl_xor(p_, 1); p_ += __shfl_xor(p_, 2);
        const float wgt = __expf((p_ + dist * wq) * 0.125f);

        // stage current tile to LDS (wave-private, no barrier)
        *(bf16x8*)&sX[wid][er*104 + q*8]      = nfA;
        *(bf16x8*)&sX[wid][er*104 + 32 + q*8] = nfB;
        *(s16x4*)&sX[wid][er*104 + 64 + q*4]  = ef4;
        if (q == 0) sX[wid][er*104 + 80] = (short)dcur;

        // ---- M1: K=96 MFMA, C-init = B[dst] (logical cols cl*4+nt) ----
        bf16x8 ax0 = *(const bf16x8*)&sX[wid][cl*104 +  0 + rg*8];
        bf16x8 ax1 = *(const bf16x8*)&sX[wid][cl*104 + 32 + rg*8];
        bf16x8 ax2 = *(const bf16x8*)&sX[wid][cl*104 + 64 + rg*8];
        f32x4 a0 = {Bb4.x,Bb4.x,Bb4.x,Bb4.x}, a1 = {Bb4.y,Bb4.y,Bb4.y,Bb4.y};
        f32x4 a2 = {Bb4.z,Bb4.z,Bb4.z,Bb4.z}, a3 = {Bb4.w,Bb4.w,Bb4.w,Bb4.w};
        a0 = MFMA(ax0, *(const bf16x8*)&sW1T[( 0+cl)*104 +  0 + rg*8], a0, 0,0,0);
        a0 = MFMA(ax1, *(const bf16x8*)&sW1T[( 0+cl)*104 + 32 + rg*8], a0, 0,0,0);
        a0 = MFMA(ax2, *(const bf16x8*)&sW1T[( 0+cl)*104 + 64 + rg*8], a0, 0,0,0);
        a1 = MFMA(ax0, *(const bf16x8*)&sW1T[(16+cl)*104 +  0 + rg*8], a1, 0,0,0);
        a1 = MFMA(ax1, *(const bf16x8*)&sW1T[(16+cl)*104 + 32 + rg*8], a1, 0,0,0);
        a1 = MFMA(ax2, *(const bf16x8*)&sW1T[(16+cl)*104 + 64 + rg*8], a1, 0,0,0);
        a2 = MFMA(ax0, *(const bf16x8*)&sW1T[(32+cl)*104 +  0 + rg*8], a2, 0,0,0);
        a2 = MFMA(ax1, *(const bf16x8*)&sW1T[(32+cl)*104 + 32 + rg*8], a2, 0,0,0);
        a2 = MFMA(ax2, *(const bf16x8*)&sW1T[(32+cl)*104 + 64 + rg*8], a2, 0,0,0);
        a3 = MFMA(ax0, *(const bf16x8*)&sW1T[(48+cl)*104 +  0 + rg*8], a3, 0,0,0);
        a3 = MFMA(ax1, *(const bf16x8*)&sW1T[(48+cl)*104 + 32 + rg*8], a3, 0,0,0);
        a3 = MFMA(ax2, *(const bf16x8*)&sW1T[(48+cl)*104 + 64 + rg*8], a3, 0,0,0);
        #pragma unroll
        for (int r = 0; r < 4; r++) {
            int row = rg*4 + r;
            float s0 = silu_fast(a0[r]), s1 = silu_fast(a1[r]);
            float s2 = silu_fast(a2[r]), s3 = silu_fast(a3[r]);
            unsigned lo, hi;
            asm("v_cvt_pk_bf16_f32 %0, %1, %2" : "=v"(lo) : "v"(s0), "v"(s1));
            asm("v_cvt_pk_bf16_f32 %0, %1, %2" : "=v"(hi) : "v"(s2), "v"(s3));
            uint2 u; u.x = lo; u.y = hi;
            *(uint2*)&sH1[wid][row*72 + cl*4] = u;   // 8B write, conflict-free
        }

        // ---- M2: msg = silu(b2 + H1 @ W2); weighted accumulate ----
        bf16x8 ah0 = *(const bf16x8*)&sH1[wid][cl*72 + rg*8];
        bf16x8 ah1 = *(const bf16x8*)&sH1[wid][cl*72 + 32 + rg*8];
        f32x4 c0v = {b24.x,b24.x,b24.x,b24.x}, c1v = {b24.y,b24.y,b24.y,b24.y};
        f32x4 c2v = {b24.z,b24.z,b24.z,b24.z}, c3v = {b24.w,b24.w,b24.w,b24.w};
        c0v = MFMA(ah0, *(const bf16x8*)&sW2T[( 0+cl)*72 +      rg*8], c0v, 0,0,0);
        c0v = MFMA(ah1, *(const bf16x8*)&sW2T[( 0+cl)*72 + 32 + rg*8], c0v, 0,0,0);
        c1v = MFMA(ah0, *(const bf16x8*)&sW2T[(16+cl)*72 +      rg*8], c1v, 0,0,0);
        c1v = MFMA(ah1, *(const bf16x8*)&sW2T[(16+cl)*72 + 32 + rg*8], c1v, 0,0,0);
        c2v = MFMA(ah0, *(const bf16x8*)&sW2T[(32+cl)*72 +      rg*8], c2v, 0,0,0);
        c2v = MFMA(ah1, *(const bf16x8*)&sW2T[(32+cl)*72 + 32 + rg*8], c2v, 0,0,0);
        c3v = MFMA(ah0, *(const bf16x8*)&sW2T[(48+cl)*72 +      rg*8], c3v, 0,0,0);
        c3v = MFMA(ah1, *(const bf16x8*)&sW2T[(48+cl)*72 + 32 + rg*8], c3v, 0,0,0);

        #pragma unroll
        for (int r = 0; r < 4; r++) {
            int row = rg*4 + r;
            float wr = (c0 + row < end) ? __shfl(wgt, row << 2) : 0.f;
            hs0 += wr * silu_fast(c0v[r]);
            hs1 += wr * silu_fast(c1v[r]);
            hs2 += wr * silu_fast(c2v[r]);
            hs3 += wr * silu_fast(c3v[r]);
            den += wr;
        }
    }

    hs0 += __shfl_xor(hs0, 16); hs0 += __shfl_xor(hs0, 32);
    hs1 += __shfl_xor(hs1, 16); hs1 += __shfl_xor(hs1, 32);
    hs2 += __shfl_xor(hs2, 16); hs2 += __shfl_xor(hs2, 32);
    hs3 += __shfl_xor(hs3, 16); hs3 += __shfl_xor(hs3, 32);
    den += __shfl_xor(den, 16); den += __shfl_xor(den, 32);

    float v = (rg == 0) ? hs0 : (rg == 1) ? hs1 : (rg == 2) ? hs2 : hs3;
    hout[nb + cl*4 + rg] = (den > 0.f) ? v / den : 0.f;   // logical col cl*4+rg
}

// ---------------- node MLP ---------------------------------------------------
__global__ __launch_bounds__(256) void node_out_kernel(
    const float* __restrict__ node_feat,
    const float* __restrict__ W_n1, const float* __restrict__ b_n1,
    const float* __restrict__ W_n2, const float* __restrict__ b_n2,
    const float* __restrict__ hacc, float* __restrict__ out)
{
    __shared__ float sWn1[128*64];
    __shared__ float sWn2[64*64];
    __shared__ __align__(16) float sx[4][64], sg[4][64], st[4][64];

    for (int i = threadIdx.x; i < 128*64; i += 256) sWn1[i] = W_n1[i];
    for (int i = threadIdx.x; i < 64*64; i += 256)  sWn2[i] = W_n2[i];
    __syncthreads();

    const int wid = threadIdx.x >> 6;
    const int lane = threadIdx.x & 63;
    for (int n = blockIdx.x * 4 + wid; n < NN; n += gridDim.x * 4) {
        sx[wid][lane] = node_feat[n*64 + lane];
        sg[wid][lane] = hacc[n*64 + lane];

        float acc = b_n1[lane];
        #pragma unroll
        for (int i = 0; i < 64; i += 4) {
            float4 x4 = *(const float4*)&sx[wid][i];
            float4 g4 = *(const float4*)&sg[wid][i];
            acc += x4.x*sWn1[(i+0)*64+lane] + x4.y*sWn1[(i+1)*64+lane]
                 + x4.z*sWn1[(i+2)*64+lane] + x4.w*sWn1[(i+3)*64+lane];
            acc += g4.x*sWn1[(64+i+0)*64+lane] + g4.y*sWn1[(64+i+1)*64+lane]
                 + g4.z*sWn1[(64+i+2)*64+lane] + g4.w*sWn1[(64+i+3)*64+lane];
        }
        const float tt = silu_f(acc);
        st[wid][lane] = tt;

        float acc2 = b_n2[lane];
        #pragma unroll
        for (int i = 0; i < 64; i += 4) {
            float4 t4 = *(const float4*)&st[wid][i];
            acc2 += t4.x*sWn2[(i+0)*64+lane] + t4.y*sWn2[(i+1)*64+lane]
                  + t4.z*sWn2[(i+2)*64+lane] + t4.w*sWn2[(i+3)*64+lane];
        }
        out[n*64 + lane] = acc2;
    }
}

// ---------------- launch -----------------------------------------------------
// Workspace layout (f32 units), all regions disjoint (36.6 MB total)
extern "C" void kernel_launch(void* const* d_in, const int* in_sizes, int n_in,
                              void* d_out, int out_size, void* d_ws, size_t ws_size,
                              hipStream_t stream) {
    const float* node_feat = (const float*)d_in[0];
    const float* coord     = (const float*)d_in[1];
    const float* edge_feat = (const float*)d_in[2];
    const float* W_e1 = (const float*)d_in[3];
    const float* b_e1 = (const float*)d_in[4];
    const float* W_e2 = (const float*)d_in[5];
    const float* b_e2 = (const float*)d_in[6];
    const float* W_n1 = (const float*)d_in[7];
    const float* b_n1 = (const float*)d_in[8];
    const float* W_n2 = (const float*)d_in[9];
    const float* b_n2 = (const float*)d_in[10];
    const float* W_q  = (const float*)d_in[11];
    const float* W_k  = (const float*)d_in[12];
    const int* src = (const int*)d_in[13];
    const int* dst = (const int*)d_in[14];
    float* out = (float*)d_out;

    float* ws = (float*)d_ws;
    short* nfb       = (short*)ws;                       // NN*64 bf16
    float* B         = ws + 320000;
    float* G         = ws + 960000;
    float* EQn       = ws + 1600000;
    float* WQn       = ws + 1760000;
    int*   cnt       = (int*)(ws + 1770000);
    int*   row_start = (int*)(ws + 1780000);
    int*   cursor    = (int*)(ws + 1790004);
    int*   perm      = (int*)(ws + 1800004);
    int*   src_s     = (int*)(ws + 2440004);
    unsigned short* dist_s = (unsigned short*)(ws + 3080004);
    unsigned short* efs    = (unsigned short*)(ws + 3400004);
    float* hacc      = ws + 8520004;

    hipMemsetAsync(cnt, 0, NN * sizeof(int), stream);

    node_pre_kernel<<<2500, 256, 0, stream>>>(node_feat, W_e1, W_k, W_q,
                                              nfb, B, G, EQn, WQn);
    k_hist<<<2500, 256, 0, stream>>>(dst, cnt);
    k_scan<<<1, 256, 0, stream>>>(cnt, row_start, cursor);
    k_scatter<<<2500, 256, 0, stream>>>(dst, cursor, perm);
    k_pack<<<2500, 256, 0, stream>>>(perm, src, dst, edge_feat, coord,
                                     src_s, dist_s, efs);
    edge_kernel<<<1250, 512, 0, stream>>>(nfb, src_s, dist_s, efs, row_start,
                                          W_e1, b_e1, W_e2, b_e2,
                                          B, G, EQn, WQn, hacc);
    node_out_kernel<<<2500, 256, 0, stream>>>(node_feat, W_n1, b_n1, W_n2, b_n2,
                                              hacc, out);
}